// Round 6
// baseline (484.928 us; speedup 1.0000x reference)
//
#include <hip/hip_runtime.h>
#include <cstdint>
#include <cstddef>

typedef __bf16 bf16;
typedef __bf16 bf16x4 __attribute__((ext_vector_type(4)));
typedef __bf16 bf16x8 __attribute__((ext_vector_type(8)));
typedef float  f32x4  __attribute__((ext_vector_type(4)));

// Direct global->LDS DMA, 16B per lane: HW writes (wave-uniform lds base) + lane*16.
#define GLD16(gptr, lptr)                                                      \
  __builtin_amdgcn_global_load_lds(                                            \
      (__attribute__((address_space(1))) unsigned int*)(gptr),                 \
      (__attribute__((address_space(3))) unsigned int*)(lptr), 16, 0, 0)

// ---------------------------------------------------------------------------
// fp32 -> bf16 conversion for the 4 big weight matrices (GLD16 needs bf16).
// ---------------------------------------------------------------------------
__global__ __launch_bounds__(256)
void convert_kernel(const float* __restrict__ src, bf16* __restrict__ dst, int n8)
{
    const int j = blockIdx.x * 256 + threadIdx.x;
    if (j >= n8) return;
    const float* s = src + (size_t)j * 8;
    bf16x8 o;
#pragma unroll
    for (int e = 0; e < 8; ++e) o[e] = (bf16)s[e];
    ((bf16x8*)dst)[j] = o;
}

// ---------------------------------------------------------------------------
// LayerNorm over H=1024, one block (256 thr) per row.
// ---------------------------------------------------------------------------
template<class InT>
__global__ __launch_bounds__(256)
void ln_kernel(const InT* __restrict__ x, const float* __restrict__ w,
               const float* __restrict__ b, bf16* __restrict__ out)
{
    __shared__ float red[8];
    const int row = blockIdx.x;
    const int tid = threadIdx.x;
    const InT* xr = x + (size_t)row * 1024;
    float xf[4], s = 0.f, ss = 0.f;
#pragma unroll
    for (int j = 0; j < 4; ++j) {
        xf[j] = (float)xr[tid * 4 + j];
        s += xf[j]; ss += xf[j] * xf[j];
    }
#pragma unroll
    for (int off = 32; off > 0; off >>= 1) { s += __shfl_xor(s, off); ss += __shfl_xor(ss, off); }
    if ((tid & 63) == 0) { red[(tid >> 6) * 2] = s; red[(tid >> 6) * 2 + 1] = ss; }
    __syncthreads();
    s  = red[0] + red[2] + red[4] + red[6];
    ss = red[1] + red[3] + red[5] + red[7];
    const float mu   = s * (1.f / 1024.f);
    const float var  = ss * (1.f / 1024.f) - mu * mu;
    const float rstd = rsqrtf(var + 1e-12f);
    bf16x4 ov;
#pragma unroll
    for (int j = 0; j < 4; ++j)
        ov[j] = (bf16)((xf[j] - mu) * rstd * w[tid * 4 + j] + b[tid * 4 + j]);
    *(bf16x4*)(out + (size_t)row * 1024 + tid * 4) = ov;
}

// ---------------------------------------------------------------------------
// m97-structure GEMM: C[M,N] = A[M,K] @ W[N,K]^T + bias (+ res).
// RES_MODE: 0 none, 1 fp32 residual, 2 bf16 residual. OUT_F32: fp32 store.
// ---------------------------------------------------------------------------
template<int RES_MODE, bool OUT_F32>
__global__ __launch_bounds__(256)
void gemm_bt(const bf16* __restrict__ A, const bf16* __restrict__ W,
             const float* __restrict__ bias, const void* __restrict__ res,
             void* __restrict__ Cv, int M, int N, int K)
{
    __shared__ alignas(16) bf16 As[128][32];
    __shared__ alignas(16) bf16 Bs[128][32];
    const int tid  = threadIdx.x;
    const int lane = tid & 63, wid = tid >> 6;
    const int lr = lane & 15, lg = lane >> 4;
    const int kgrp = lg * 8;
    const int wm = (wid >> 1) * 64, wn = (wid & 1) * 64;
    const int row0 = blockIdx.x * 128, col0 = blockIdx.y * 128;

    f32x4 acc[4][4] = {};

    for (int k0 = 0; k0 < K; k0 += 32) {
#pragma unroll
        for (int i = 0; i < 2; ++i) {
            const int c = i * 256 + tid;
            const int r = c >> 2, k8 = (c & 3) * 8;
            GLD16(A + (size_t)(row0 + r) * K + k0 + k8,
                  (char*)&As[0][0] + (size_t)(i * 256 + wid * 64) * 16);
            GLD16(W + (size_t)(col0 + r) * K + k0 + k8,
                  (char*)&Bs[0][0] + (size_t)(i * 256 + wid * 64) * 16);
        }
        __syncthreads();
        bf16x8 af[4], bw[4];
#pragma unroll
        for (int mi = 0; mi < 4; ++mi) af[mi] = *(const bf16x8*)&As[wm + mi * 16 + lr][kgrp];
#pragma unroll
        for (int ni = 0; ni < 4; ++ni) bw[ni] = *(const bf16x8*)&Bs[wn + ni * 16 + lr][kgrp];
#pragma unroll
        for (int mi = 0; mi < 4; ++mi)
#pragma unroll
            for (int ni = 0; ni < 4; ++ni)
                acc[mi][ni] = __builtin_amdgcn_mfma_f32_16x16x32_bf16(
                    af[mi], bw[ni], acc[mi][ni], 0, 0, 0);
        __syncthreads();
    }

    // C/D layout: col = lane&15, row = (lane>>4)*4 + reg
#pragma unroll
    for (int ni = 0; ni < 4; ++ni) {
        const int ccol = col0 + wn + ni * 16 + lr;
        const float bv = bias[ccol];
#pragma unroll
        for (int mi = 0; mi < 4; ++mi)
#pragma unroll
            for (int r = 0; r < 4; ++r) {
                const size_t crow = (size_t)(row0 + wm + mi * 16 + lg * 4 + r);
                float v = acc[mi][ni][r] + bv;
                if constexpr (RES_MODE == 1) v += ((const float*)res)[crow * N + ccol];
                if constexpr (RES_MODE == 2) v += (float)((const bf16*)res)[crow * N + ccol];
                if constexpr (OUT_F32) ((float*)Cv)[crow * N + ccol] = v;
                else                   ((bf16*)Cv)[crow * N + ccol] = (bf16)v;
            }
    }
}

// ---------------------------------------------------------------------------
// QKV GEMM (m97 structure) with fused RoPE + head-rearrange epilogue.
// qkv cols: [0,1024) q, [1024,2048) k, [2048,3072) v  (blockIdx.y/8 selects).
// Each thread's acc holds head-col pair (i, i+32) at (ni, ni+2): rotate in
// registers, scatter to q_r/k_r/v_r [64 bh][1024 s][64 hd].
// ---------------------------------------------------------------------------
__global__ __launch_bounds__(256)
void gemm_qkv_rope(const bf16* __restrict__ A, const bf16* __restrict__ W,
                   const float* __restrict__ bias, bf16* __restrict__ q_r,
                   bf16* __restrict__ k_r, bf16* __restrict__ v_r)
{
    __shared__ alignas(16) bf16 As[128][32];
    __shared__ alignas(16) bf16 Bs[128][32];
    const int tid  = threadIdx.x;
    const int lane = tid & 63, wid = tid >> 6;
    const int lr = lane & 15, lg = lane >> 4;
    const int kgrp = lg * 8;
    const int wm = (wid >> 1) * 64, wn = (wid & 1) * 64;
    const int row0 = blockIdx.x * 128, col0 = blockIdx.y * 128;
    const int K = 1024;

    f32x4 acc[4][4] = {};

    for (int k0 = 0; k0 < K; k0 += 32) {
#pragma unroll
        for (int i = 0; i < 2; ++i) {
            const int c = i * 256 + tid;
            const int r = c >> 2, k8 = (c & 3) * 8;
            GLD16(A + (size_t)(row0 + r) * K + k0 + k8,
                  (char*)&As[0][0] + (size_t)(i * 256 + wid * 64) * 16);
            GLD16(W + (size_t)(col0 + r) * K + k0 + k8,
                  (char*)&Bs[0][0] + (size_t)(i * 256 + wid * 64) * 16);
        }
        __syncthreads();
        bf16x8 af[4], bw[4];
#pragma unroll
        for (int mi = 0; mi < 4; ++mi) af[mi] = *(const bf16x8*)&As[wm + mi * 16 + lr][kgrp];
#pragma unroll
        for (int ni = 0; ni < 4; ++ni) bw[ni] = *(const bf16x8*)&Bs[wn + ni * 16 + lr][kgrp];
#pragma unroll
        for (int mi = 0; mi < 4; ++mi)
#pragma unroll
            for (int ni = 0; ni < 4; ++ni)
                acc[mi][ni] = __builtin_amdgcn_mfma_f32_16x16x32_bf16(
                    af[mi], bw[ni], acc[mi][ni], 0, 0, 0);
        __syncthreads();
    }

    const int third = blockIdx.y >> 3;               // 0 q, 1 k, 2 v
    bf16* dst = (third == 0) ? q_r : (third == 1) ? k_r : v_r;
#pragma unroll
    for (int ni = 0; ni < 2; ++ni) {
        const int i_ = ni * 16 + lr;                 // head-local col 0..31
        const int ccol = col0 + wn + ni * 16 + lr;   // global qkv col (low half)
        const int h = (ccol >> 6) & 15;
        const float blo = bias[ccol], bhi = bias[ccol + 32];
        const float inv = __expf((float)i_ * (-9.210340371976184f / 32.f));
#pragma unroll
        for (int mi = 0; mi < 4; ++mi)
#pragma unroll
            for (int r = 0; r < 4; ++r) {
                const int crow = row0 + wm + mi * 16 + lg * 4 + r;
                const int s = crow & 1023, b = crow >> 10;
                const float lo = acc[mi][ni][r] + blo;
                const float hi = acc[mi][ni + 2][r] + bhi;
                const size_t ob = ((size_t)(b * 16 + h) * 1024 + s) * 64;
                if (third == 2) {
                    dst[ob + i_]      = (bf16)lo;
                    dst[ob + i_ + 32] = (bf16)hi;
                } else {
                    float sn, c;
                    sincosf((float)s * inv, &sn, &c);
                    dst[ob + i_]      = (bf16)(lo * c - hi * sn);
                    dst[ob + i_ + 32] = (bf16)(hi * c + lo * sn);
                }
            }
    }
}

// ---------------------------------------------------------------------------
// i2h + gated exact-GELU, 8-phase-style pipelined GEMM (T2+T3+T4+T5).
// Block: 256 A-rows x 128 hid-cols (gate + lin => effective 256x256 tile).
// 8 waves (2 row x 4 col). BK=32, 3-stage LDS pipeline (3 x 32 KB = 96 KB),
// counted vmcnt(4) at tile boundary (never drain-0 in steady state).
// LDS XOR-swizzle bc ^= ((row>>1)&3)<<4 applied to DMA *source* and ds_read
// (both-sides rule): 2-way bank aliasing (free) instead of 8/16-way.
// Audited: uniform barriers, vmcnt ledger 8->4, WAR-safe 3-buffer rotation,
// asm "memory" clobbers pin all reordering, no OOB. (R5 fail was infra.)
// ---------------------------------------------------------------------------
__global__ __launch_bounds__(512, 2)
void gemm_i2h_g8(const bf16* __restrict__ A, const bf16* __restrict__ W,
                 const float* __restrict__ bias, bf16* __restrict__ hid)
{
    __shared__ alignas(16) char smem[3 * 32768];   // per buf: A 16K | Bg 8K | Bl 8K
    const int tid  = threadIdx.x;
    const int lane = tid & 63, wid = tid >> 6;
    const int lrr  = lane & 15, lg = lane >> 4;
    const int wr = wid >> 2, wc = wid & 3;         // 2x4 wave grid
    const int row0 = blockIdx.x * 256;             // A rows
    const int colh = blockIdx.y * 128 + wc * 32;   // hid col base for this wave
    const int NT = 32;                             // K / 32

    // ---- staging geometry (per-thread constants) ----
    // A: 256 rows x 32 k x 2B = 16 KB = 1024 chunks of 16B (2/thread)
    // Bg/Bl: 128 rows x 32 k x 2B = 8 KB = 512 chunks (1/thread each)
    const int cA0 = tid, cA1 = 512 + tid;
    const int rA0 = cA0 >> 2, rA1 = cA1 >> 2, rB = tid >> 2;
    const int swA0 = (((cA0 & 3) * 16) ^ (((rA0 >> 1) & 3) << 4)) >> 1;  // elems
    const int swA1 = (((cA1 & 3) * 16) ^ (((rA1 >> 1) & 3) << 4)) >> 1;
    const int swB  = (((tid & 3) * 16) ^ (((rB  >> 1) & 3) << 4)) >> 1;
    const bf16* gA0 = A + (size_t)(row0 + rA0) * 1024 + swA0;
    const bf16* gA1 = A + (size_t)(row0 + rA1) * 1024 + swA1;
    const bf16* gBg = W + (size_t)(blockIdx.y * 128 + rB) * 1024 + swB;
    const bf16* gBl = W + (size_t)(4096 + blockIdx.y * 128 + rB) * 1024 + swB;
    // wave-uniform LDS dest offsets (HW adds lane*16)
    const int dA0 = (wid * 64) * 16, dA1 = (512 + wid * 64) * 16, dB = (wid * 64) * 16;

    f32x4 acc[8][4] = {};   // [m-frag][nv: 0,1 gate c0,c1; 2,3 lin c0,c1]

    // prologue: stage tiles 0 and 1
    {
        char* b0 = smem;
        GLD16(gBg, b0 + 16384 + dB); GLD16(gBl, b0 + 24576 + dB);
        GLD16(gA0, b0 + dA0);        GLD16(gA1, b0 + dA1);
        char* b1 = smem + 32768;
        GLD16(gBg + 32, b1 + 16384 + dB); GLD16(gBl + 32, b1 + 24576 + dB);
        GLD16(gA0 + 32, b1 + dA0);        GLD16(gA1 + 32, b1 + dA1);
    }
    asm volatile("s_waitcnt vmcnt(4)\ns_barrier" ::: "memory");

    int cur = 0, stg = 2;
    for (int t = 0; t < NT; ++t) {
        const char* bA  = smem + cur * 32768;
        const char* bBg = bA + 16384;
        const char* bBl = bA + 24576;
        char* sB = smem + stg * 32768;
        const int k0s = (t + 2) * 32;
        const bool dostg = (t < NT - 2);

        // ---------------- phase 0: B frags + A frags m0..3 -----------------
        if (dostg) { GLD16(gBg + k0s, sB + 16384 + dB); GLD16(gBl + k0s, sB + 24576 + dB); }
        bf16x8 bf[4], af[4];
        const int bcol = lg * 16;
#pragma unroll
        for (int nv = 0; nv < 4; ++nv) {
            const int row = wc * 32 + (nv & 1) * 16 + lrr;
            const char* base = (nv < 2) ? bBg : bBl;
            bf[nv] = *(const bf16x8*)(base + row * 64 + (bcol ^ (((row >> 1) & 3) << 4)));
        }
#pragma unroll
        for (int mi = 0; mi < 4; ++mi) {
            const int row = wr * 128 + mi * 16 + lrr;
            af[mi] = *(const bf16x8*)(bA + row * 64 + (bcol ^ (((row >> 1) & 3) << 4)));
        }
        __builtin_amdgcn_s_barrier();
        __builtin_amdgcn_s_setprio(1);
#pragma unroll
        for (int mi = 0; mi < 4; ++mi)
#pragma unroll
            for (int nv = 0; nv < 4; ++nv)
                acc[mi][nv] = __builtin_amdgcn_mfma_f32_16x16x32_bf16(
                    af[mi], bf[nv], acc[mi][nv], 0, 0, 0);
        __builtin_amdgcn_s_setprio(0);
        __builtin_amdgcn_s_barrier();

        // ---------------- phase 1: A frags m4..7 ---------------------------
        if (dostg) { GLD16(gA0 + k0s, sB + dA0); GLD16(gA1 + k0s, sB + dA1); }
#pragma unroll
        for (int mi = 0; mi < 4; ++mi) {
            const int row = wr * 128 + (4 + mi) * 16 + lrr;
            af[mi] = *(const bf16x8*)(bA + row * 64 + (bcol ^ (((row >> 1) & 3) << 4)));
        }
        __builtin_amdgcn_s_barrier();
        __builtin_amdgcn_s_setprio(1);
#pragma unroll
        for (int mi = 0; mi < 4; ++mi)
#pragma unroll
            for (int nv = 0; nv < 4; ++nv)
                acc[4 + mi][nv] = __builtin_amdgcn_mfma_f32_16x16x32_bf16(
                    af[mi], bf[nv], acc[4 + mi][nv], 0, 0, 0);
        __builtin_amdgcn_s_setprio(0);

        // tile boundary: counted vmcnt (batch t+2 stays in flight), barrier.
        if (dostg) asm volatile("s_waitcnt vmcnt(4)\ns_barrier" ::: "memory");
        else       asm volatile("s_waitcnt vmcnt(0)\ns_barrier" ::: "memory");
        cur = (cur == 2) ? 0 : cur + 1;
        stg = (stg == 2) ? 0 : stg + 1;
    }

    // epilogue: hid = gelu(gate)*lin, fp32 pre-rounding
#pragma unroll
    for (int c = 0; c < 2; ++c) {
        const int gcol = colh + c * 16 + lrr;
        const float bg_ = bias[gcol], bl_ = bias[4096 + gcol];
#pragma unroll
        for (int mi = 0; mi < 8; ++mi)
#pragma unroll
            for (int r = 0; r < 4; ++r) {
                const size_t row = (size_t)(row0 + wr * 128 + mi * 16 + lg * 4 + r);
                const float g = acc[mi][c][r] + bg_;
                const float l = acc[mi][2 + c][r] + bl_;
                const float ge = 0.5f * g * (1.f + erff(g * 0.70710678118654752f));
                hid[row * 4096 + gcol] = (bf16)(ge * l);
            }
    }
}

// ---------------------------------------------------------------------------
// Flash attention, causal, scale=1/8. Block = 4 waves = 64 q-rows of one
// (b,head). KV chunks of 64. LDS rows padded to 72 elems.
// ---------------------------------------------------------------------------
__global__ __launch_bounds__(256)
void attn_kernel(const bf16* __restrict__ q_r, const bf16* __restrict__ k_r,
                 const bf16* __restrict__ v_r, bf16* __restrict__ attn)
{
    __shared__ alignas(16) bf16 Ks[64][72];
    __shared__ alignas(16) bf16 Vt[64][72];
    __shared__ alignas(16) bf16 Ps[4][16][72];
    const int qt = blockIdx.x, bh = blockIdx.y;
    const int tid = threadIdx.x, lane = tid & 63, w = tid >> 6;
    const int lr = lane & 15, lg = lane >> 4;
    const int kgrp = lg * 8;
    const int qbase = qt * 64;

    const bf16* qrow = q_r + ((size_t)bh * 1024 + qbase + w * 16 + lr) * 64;
    const bf16x8 qf0 = *(const bf16x8*)(qrow + kgrp);
    const bf16x8 qf1 = *(const bf16x8*)(qrow + 32 + kgrp);

    f32x4 o[4] = {};
    float m_r[4], l_r[4];
#pragma unroll
    for (int r = 0; r < 4; ++r) { m_r[r] = -1e30f; l_r[r] = 0.f; }

    const int nchunk = qt + 1;
    for (int ic = 0; ic < nchunk; ++ic) {
        const int kb = ic * 64;
        __syncthreads();
#pragma unroll
        for (int i = 0; i < 2; ++i) {
            const int c = i * 256 + tid;
            const int row = c >> 3, e8 = (c & 7) * 8;
            *(bf16x8*)&Ks[row][e8] =
                *(const bf16x8*)(k_r + ((size_t)bh * 1024 + kb + row) * 64 + e8);
            const bf16x8 vv =
                *(const bf16x8*)(v_r + ((size_t)bh * 1024 + kb + row) * 64 + e8);
#pragma unroll
            for (int j = 0; j < 8; ++j) Vt[e8 + j][row] = vv[j];
        }
        __syncthreads();

        f32x4 sv[4] = {};
#pragma unroll
        for (int nb = 0; nb < 4; ++nb) {
            const bf16x8 kf0 = *(const bf16x8*)&Ks[nb * 16 + lr][kgrp];
            const bf16x8 kf1 = *(const bf16x8*)&Ks[nb * 16 + lr][32 + kgrp];
            sv[nb] = __builtin_amdgcn_mfma_f32_16x16x32_bf16(qf0, kf0, sv[nb], 0, 0, 0);
            sv[nb] = __builtin_amdgcn_mfma_f32_16x16x32_bf16(qf1, kf1, sv[nb], 0, 0, 0);
        }

        const bool diag = (kb == qbase);
        float pv[4][4];
#pragma unroll
        for (int r = 0; r < 4; ++r) {
            float s0[4];
#pragma unroll
            for (int nb = 0; nb < 4; ++nb) {
                float t = sv[nb][r] * 0.125f;
                if (diag && (nb * 16 + lr) > (w * 16 + lg * 4 + r)) t = -10000.f;
                s0[nb] = t;
            }
            float rm = fmaxf(fmaxf(s0[0], s0[1]), fmaxf(s0[2], s0[3]));
#pragma unroll
            for (int off = 1; off < 16; off <<= 1) rm = fmaxf(rm, __shfl_xor(rm, off));
            const float nm = fmaxf(m_r[r], rm);
            const float sc = __expf(m_r[r] - nm);
            float rs = 0.f;
#pragma unroll
            for (int nb = 0; nb < 4; ++nb) {
                const float p = __expf(s0[nb] - nm);
                pv[nb][r] = p; rs += p;
            }
#pragma unroll
            for (int off = 1; off < 16; off <<= 1) rs += __shfl_xor(rs, off);
            l_r[r] = l_r[r] * sc + rs;
            m_r[r] = nm;
#pragma unroll
            for (int nb = 0; nb < 4; ++nb) o[nb][r] *= sc;
        }

#pragma unroll
        for (int nb = 0; nb < 4; ++nb)
#pragma unroll
            for (int r = 0; r < 4; ++r)
                Ps[w][lg * 4 + r][nb * 16 + lr] = (bf16)pv[nb][r];
#pragma unroll
        for (int nb = 0; nb < 4; ++nb)
#pragma unroll
            for (int ks = 0; ks < 2; ++ks) {
                const bf16x8 pa = *(const bf16x8*)&Ps[w][lr][ks * 32 + kgrp];
                const bf16x8 vb = *(const bf16x8*)&Vt[nb * 16 + lr][ks * 32 + kgrp];
                o[nb] = __builtin_amdgcn_mfma_f32_16x16x32_bf16(pa, vb, o[nb], 0, 0, 0);
            }
    }

    const int b = bh >> 4, head = bh & 15;
#pragma unroll
    for (int nb = 0; nb < 4; ++nb)
#pragma unroll
        for (int r = 0; r < 4; ++r) {
            const size_t rw = (size_t)(b * 1024 + qbase + w * 16 + lg * 4 + r);
            attn[rw * 1024 + head * 64 + nb * 16 + lr] = (bf16)(o[nb][r] / l_r[r]);
        }
}

// ---------------------------------------------------------------------------
extern "C" void kernel_launch(void* const* d_in, const int* in_sizes, int n_in,
                              void* d_out, int out_size, void* d_ws, size_t ws_size,
                              hipStream_t stream)
{
    const float* x    = (const float*)d_in[0];
    const float* ln1w = (const float*)d_in[1];
    const float* ln1b = (const float*)d_in[2];
    const float* qkvw = (const float*)d_in[3];
    const float* qkvb = (const float*)d_in[4];
    const float* outw = (const float*)d_in[5];
    const float* outb = (const float*)d_in[6];
    const float* ln2w = (const float*)d_in[7];
    const float* ln2b = (const float*)d_in[8];
    const float* i2hw = (const float*)d_in[9];
    const float* i2hb = (const float*)d_in[10];
    const float* h2ow = (const float*)d_in[11];
    const float* h2ob = (const float*)d_in[12];

    char* ws = (char*)d_ws;
    const size_t MB = 1024 * 1024;

    bf16* h_ln    = (bf16*)(ws + 0);         //  8 MB
    bf16* q_r     = (bf16*)(ws + 8 * MB);    //  8 MB
    bf16* k_r     = (bf16*)(ws + 16 * MB);   //  8 MB
    bf16* v_r     = (bf16*)(ws + 24 * MB);   //  8 MB
    bf16* attn    = (bf16*)(ws + 32 * MB);   //  8 MB
    bf16* attnout = (bf16*)(ws + 40 * MB);   //  8 MB
    bf16* ffnln   = (bf16*)(ws + 48 * MB);   //  8 MB
    bf16* hid     = (bf16*)(ws + 56 * MB);   // 32 MB
    bf16* qkvw_c  = (bf16*)(ws + 88 * MB);   //  6 MB
    bf16* outw_c  = (bf16*)(ws + 94 * MB);   //  2 MB
    bf16* i2hw_c  = (bf16*)(ws + 96 * MB);   // 16 MB
    bf16* h2ow_c  = (bf16*)(ws + 112 * MB);  //  8 MB (total 120 MB)

    convert_kernel<<<1536, 256, 0, stream>>>(qkvw, qkvw_c, 3145728 / 8);
    convert_kernel<<< 512, 256, 0, stream>>>(outw, outw_c, 1048576 / 8);
    convert_kernel<<<4096, 256, 0, stream>>>(i2hw, i2hw_c, 8388608 / 8);
    convert_kernel<<<2048, 256, 0, stream>>>(h2ow, h2ow_c, 4194304 / 8);

    ln_kernel<float><<<4096, 256, 0, stream>>>(x, ln1w, ln1b, h_ln);
    gemm_qkv_rope<<<dim3(32, 24), 256, 0, stream>>>(h_ln, qkvw_c, qkvb,
                                                    q_r, k_r, v_r);
    attn_kernel<<<dim3(16, 64), 256, 0, stream>>>(q_r, k_r, v_r, attn);
    gemm_bt<1, false><<<dim3(32, 8), 256, 0, stream>>>(
        attn, outw_c, outb, x, attnout, 4096, 1024, 1024);
    ln_kernel<bf16><<<4096, 256, 0, stream>>>(attnout, ln2w, ln2b, ffnln);
    gemm_i2h_g8<<<dim3(16, 32), 512, 0, stream>>>(ffnln, i2hw_c, i2hb, hid);
    gemm_bt<2, true><<<dim3(32, 8), 256, 0, stream>>>(
        hid, h2ow_c, h2ob, attnout, d_out, 4096, 1024, 4096);
}

// Round 8
// 473.072 us; speedup vs baseline: 1.0251x; 1.0251x over previous
//
#include <hip/hip_runtime.h>
#include <cstdint>
#include <cstddef>

typedef __bf16 bf16;
typedef __bf16 bf16x4 __attribute__((ext_vector_type(4)));
typedef __bf16 bf16x8 __attribute__((ext_vector_type(8)));
typedef float  f32x4  __attribute__((ext_vector_type(4)));

// Direct global->LDS DMA, 16B per lane: HW writes (wave-uniform lds base) + lane*16.
#define GLD16(gptr, lptr)                                                      \
  __builtin_amdgcn_global_load_lds(                                            \
      (__attribute__((address_space(1))) unsigned int*)(gptr),                 \
      (__attribute__((address_space(3))) unsigned int*)(lptr), 16, 0, 0)

// ---------------------------------------------------------------------------
// fp32 -> bf16 conversion for the 4 big weight matrices (GLD16 needs bf16).
// ---------------------------------------------------------------------------
__global__ __launch_bounds__(256)
void convert_kernel(const float* __restrict__ src, bf16* __restrict__ dst, int n8)
{
    const int j = blockIdx.x * 256 + threadIdx.x;
    if (j >= n8) return;
    const float* s = src + (size_t)j * 8;
    bf16x8 o;
#pragma unroll
    for (int e = 0; e < 8; ++e) o[e] = (bf16)s[e];
    ((bf16x8*)dst)[j] = o;
}

// ---------------------------------------------------------------------------
// LayerNorm over H=1024, one block (256 thr) per row.
// ---------------------------------------------------------------------------
template<class InT>
__global__ __launch_bounds__(256)
void ln_kernel(const InT* __restrict__ x, const float* __restrict__ w,
               const float* __restrict__ b, bf16* __restrict__ out)
{
    __shared__ float red[8];
    const int row = blockIdx.x;
    const int tid = threadIdx.x;
    const InT* xr = x + (size_t)row * 1024;
    float xf[4], s = 0.f, ss = 0.f;
#pragma unroll
    for (int j = 0; j < 4; ++j) {
        xf[j] = (float)xr[tid * 4 + j];
        s += xf[j]; ss += xf[j] * xf[j];
    }
#pragma unroll
    for (int off = 32; off > 0; off >>= 1) { s += __shfl_xor(s, off); ss += __shfl_xor(ss, off); }
    if ((tid & 63) == 0) { red[(tid >> 6) * 2] = s; red[(tid >> 6) * 2 + 1] = ss; }
    __syncthreads();
    s  = red[0] + red[2] + red[4] + red[6];
    ss = red[1] + red[3] + red[5] + red[7];
    const float mu   = s * (1.f / 1024.f);
    const float var  = ss * (1.f / 1024.f) - mu * mu;
    const float rstd = rsqrtf(var + 1e-12f);
    bf16x4 ov;
#pragma unroll
    for (int j = 0; j < 4; ++j)
        ov[j] = (bf16)((xf[j] - mu) * rstd * w[tid * 4 + j] + b[tid * 4 + j]);
    *(bf16x4*)(out + (size_t)row * 1024 + tid * 4) = ov;
}

// ---------------------------------------------------------------------------
// m97-structure GEMM: C[M,N] = A[M,K] @ W[N,K]^T + bias (+ res).
// RES_MODE: 0 none, 1 fp32 residual, 2 bf16 residual. OUT_F32: fp32 store.
// ---------------------------------------------------------------------------
template<int RES_MODE, bool OUT_F32>
__global__ __launch_bounds__(256)
void gemm_bt(const bf16* __restrict__ A, const bf16* __restrict__ W,
             const float* __restrict__ bias, const void* __restrict__ res,
             void* __restrict__ Cv, int M, int N, int K)
{
    __shared__ alignas(16) bf16 As[128][32];
    __shared__ alignas(16) bf16 Bs[128][32];
    const int tid  = threadIdx.x;
    const int lane = tid & 63, wid = tid >> 6;
    const int lr = lane & 15, lg = lane >> 4;
    const int kgrp = lg * 8;
    const int wm = (wid >> 1) * 64, wn = (wid & 1) * 64;
    const int row0 = blockIdx.x * 128, col0 = blockIdx.y * 128;

    f32x4 acc[4][4] = {};

    for (int k0 = 0; k0 < K; k0 += 32) {
#pragma unroll
        for (int i = 0; i < 2; ++i) {
            const int c = i * 256 + tid;
            const int r = c >> 2, k8 = (c & 3) * 8;
            GLD16(A + (size_t)(row0 + r) * K + k0 + k8,
                  (char*)&As[0][0] + (size_t)(i * 256 + wid * 64) * 16);
            GLD16(W + (size_t)(col0 + r) * K + k0 + k8,
                  (char*)&Bs[0][0] + (size_t)(i * 256 + wid * 64) * 16);
        }
        __syncthreads();
        bf16x8 af[4], bw[4];
#pragma unroll
        for (int mi = 0; mi < 4; ++mi) af[mi] = *(const bf16x8*)&As[wm + mi * 16 + lr][kgrp];
#pragma unroll
        for (int ni = 0; ni < 4; ++ni) bw[ni] = *(const bf16x8*)&Bs[wn + ni * 16 + lr][kgrp];
#pragma unroll
        for (int mi = 0; mi < 4; ++mi)
#pragma unroll
            for (int ni = 0; ni < 4; ++ni)
                acc[mi][ni] = __builtin_amdgcn_mfma_f32_16x16x32_bf16(
                    af[mi], bw[ni], acc[mi][ni], 0, 0, 0);
        __syncthreads();
    }

    // C/D layout: col = lane&15, row = (lane>>4)*4 + reg
#pragma unroll
    for (int ni = 0; ni < 4; ++ni) {
        const int ccol = col0 + wn + ni * 16 + lr;
        const float bv = bias[ccol];
#pragma unroll
        for (int mi = 0; mi < 4; ++mi)
#pragma unroll
            for (int r = 0; r < 4; ++r) {
                const size_t crow = (size_t)(row0 + wm + mi * 16 + lg * 4 + r);
                float v = acc[mi][ni][r] + bv;
                if constexpr (RES_MODE == 1) v += ((const float*)res)[crow * N + ccol];
                if constexpr (RES_MODE == 2) v += (float)((const bf16*)res)[crow * N + ccol];
                if constexpr (OUT_F32) ((float*)Cv)[crow * N + ccol] = v;
                else                   ((bf16*)Cv)[crow * N + ccol] = (bf16)v;
            }
    }
}

// ---------------------------------------------------------------------------
// Split-K GEMM for h2o: M=4096, N=1024, K=4096 split into 4 x 1024.
// Grid (32, 8, 4) = 1024 blocks (4/CU vs 1/CU unsplit — the R6 bottleneck:
// occupancy 10.6%, MfmaUtil 14%). Raw fp32 partials, no bias.
// ---------------------------------------------------------------------------
__global__ __launch_bounds__(256)
void gemm_h2o_sk(const bf16* __restrict__ A, const bf16* __restrict__ W,
                 float* __restrict__ part)
{
    __shared__ alignas(16) bf16 As[128][32];
    __shared__ alignas(16) bf16 Bs[128][32];
    const int tid  = threadIdx.x;
    const int lane = tid & 63, wid = tid >> 6;
    const int lr = lane & 15, lg = lane >> 4;
    const int kgrp = lg * 8;
    const int wm = (wid >> 1) * 64, wn = (wid & 1) * 64;
    const int row0 = blockIdx.x * 128, col0 = blockIdx.y * 128;
    const int kbase = blockIdx.z * 1024;          // K-split origin
    const int K = 4096;

    f32x4 acc[4][4] = {};

    for (int k0 = kbase; k0 < kbase + 1024; k0 += 32) {
#pragma unroll
        for (int i = 0; i < 2; ++i) {
            const int c = i * 256 + tid;
            const int r = c >> 2, k8 = (c & 3) * 8;
            GLD16(A + (size_t)(row0 + r) * K + k0 + k8,
                  (char*)&As[0][0] + (size_t)(i * 256 + wid * 64) * 16);
            GLD16(W + (size_t)(col0 + r) * K + k0 + k8,
                  (char*)&Bs[0][0] + (size_t)(i * 256 + wid * 64) * 16);
        }
        __syncthreads();
        bf16x8 af[4], bw[4];
#pragma unroll
        for (int mi = 0; mi < 4; ++mi) af[mi] = *(const bf16x8*)&As[wm + mi * 16 + lr][kgrp];
#pragma unroll
        for (int ni = 0; ni < 4; ++ni) bw[ni] = *(const bf16x8*)&Bs[wn + ni * 16 + lr][kgrp];
#pragma unroll
        for (int mi = 0; mi < 4; ++mi)
#pragma unroll
            for (int ni = 0; ni < 4; ++ni)
                acc[mi][ni] = __builtin_amdgcn_mfma_f32_16x16x32_bf16(
                    af[mi], bw[ni], acc[mi][ni], 0, 0, 0);
        __syncthreads();
    }

    float* dst = part + (size_t)blockIdx.z * 4096 * 1024;
#pragma unroll
    for (int ni = 0; ni < 4; ++ni) {
        const int ccol = col0 + wn + ni * 16 + lr;
#pragma unroll
        for (int mi = 0; mi < 4; ++mi)
#pragma unroll
            for (int r = 0; r < 4; ++r) {
                const size_t crow = (size_t)(row0 + wm + mi * 16 + lg * 4 + r);
                dst[crow * 1024 + ccol] = acc[mi][ni][r];
            }
    }
}

// ---------------------------------------------------------------------------
// Split-K reduce: out = sum(4 partials) + bias + attnout residual (fp32 out).
// 4 cols per thread via float4.
// ---------------------------------------------------------------------------
__global__ __launch_bounds__(256)
void h2o_reduce(const float* __restrict__ part, const float* __restrict__ bias,
                const bf16* __restrict__ res, float* __restrict__ out)
{
    const size_t g = ((size_t)blockIdx.x * 256 + threadIdx.x) * 4;
    const int col = (int)(g & 1023);
    f32x4 v = *(const f32x4*)(part + g);
#pragma unroll
    for (int s = 1; s < 4; ++s) {
        const f32x4 p = *(const f32x4*)(part + (size_t)s * 4096 * 1024 + g);
#pragma unroll
        for (int j = 0; j < 4; ++j) v[j] += p[j];
    }
    const f32x4 bv = *(const f32x4*)(bias + col);
    const bf16x4 rv = *(const bf16x4*)(res + g);
    f32x4 o;
#pragma unroll
    for (int j = 0; j < 4; ++j) o[j] = v[j] + bv[j] + (float)rv[j];
    *(f32x4*)(out + g) = o;
}

// ---------------------------------------------------------------------------
// QKV GEMM (m97 structure) with fused RoPE + head-rearrange epilogue.
// qkv cols: [0,1024) q, [1024,2048) k, [2048,3072) v  (blockIdx.y/8 selects).
// Each thread's acc holds head-col pair (i, i+32) at (ni, ni+2): rotate in
// registers, scatter to q_r/k_r/v_r [64 bh][1024 s][64 hd].
// Attention scale 1/8 folded into the q store (rotation is linear).
// ---------------------------------------------------------------------------
__global__ __launch_bounds__(256)
void gemm_qkv_rope(const bf16* __restrict__ A, const bf16* __restrict__ W,
                   const float* __restrict__ bias, bf16* __restrict__ q_r,
                   bf16* __restrict__ k_r, bf16* __restrict__ v_r)
{
    __shared__ alignas(16) bf16 As[128][32];
    __shared__ alignas(16) bf16 Bs[128][32];
    const int tid  = threadIdx.x;
    const int lane = tid & 63, wid = tid >> 6;
    const int lr = lane & 15, lg = lane >> 4;
    const int kgrp = lg * 8;
    const int wm = (wid >> 1) * 64, wn = (wid & 1) * 64;
    const int row0 = blockIdx.x * 128, col0 = blockIdx.y * 128;
    const int K = 1024;

    f32x4 acc[4][4] = {};

    for (int k0 = 0; k0 < K; k0 += 32) {
#pragma unroll
        for (int i = 0; i < 2; ++i) {
            const int c = i * 256 + tid;
            const int r = c >> 2, k8 = (c & 3) * 8;
            GLD16(A + (size_t)(row0 + r) * K + k0 + k8,
                  (char*)&As[0][0] + (size_t)(i * 256 + wid * 64) * 16);
            GLD16(W + (size_t)(col0 + r) * K + k0 + k8,
                  (char*)&Bs[0][0] + (size_t)(i * 256 + wid * 64) * 16);
        }
        __syncthreads();
        bf16x8 af[4], bw[4];
#pragma unroll
        for (int mi = 0; mi < 4; ++mi) af[mi] = *(const bf16x8*)&As[wm + mi * 16 + lr][kgrp];
#pragma unroll
        for (int ni = 0; ni < 4; ++ni) bw[ni] = *(const bf16x8*)&Bs[wn + ni * 16 + lr][kgrp];
#pragma unroll
        for (int mi = 0; mi < 4; ++mi)
#pragma unroll
            for (int ni = 0; ni < 4; ++ni)
                acc[mi][ni] = __builtin_amdgcn_mfma_f32_16x16x32_bf16(
                    af[mi], bw[ni], acc[mi][ni], 0, 0, 0);
        __syncthreads();
    }

    const int third = blockIdx.y >> 3;               // 0 q, 1 k, 2 v
    bf16* dst = (third == 0) ? q_r : (third == 1) ? k_r : v_r;
    const float qs = (third == 0) ? 0.125f : 1.f;    // folded softmax scale
#pragma unroll
    for (int ni = 0; ni < 2; ++ni) {
        const int i_ = ni * 16 + lr;                 // head-local col 0..31
        const int ccol = col0 + wn + ni * 16 + lr;   // global qkv col (low half)
        const int h = (ccol >> 6) & 15;
        const float blo = bias[ccol], bhi = bias[ccol + 32];
        const float inv = __expf((float)i_ * (-9.210340371976184f / 32.f));
#pragma unroll
        for (int mi = 0; mi < 4; ++mi)
#pragma unroll
            for (int r = 0; r < 4; ++r) {
                const int crow = row0 + wm + mi * 16 + lg * 4 + r;
                const int s = crow & 1023, b = crow >> 10;
                const float lo = acc[mi][ni][r] + blo;
                const float hi = acc[mi][ni + 2][r] + bhi;
                const size_t ob = ((size_t)(b * 16 + h) * 1024 + s) * 64;
                if (third == 2) {
                    dst[ob + i_]      = (bf16)lo;
                    dst[ob + i_ + 32] = (bf16)hi;
                } else {
                    float sn, c;
                    sincosf((float)s * inv, &sn, &c);
                    dst[ob + i_]      = (bf16)((lo * c - hi * sn) * qs);
                    dst[ob + i_ + 32] = (bf16)((hi * c + lo * sn) * qs);
                }
            }
    }
}

// ---------------------------------------------------------------------------
// i2h + gated exact-GELU, pipelined GEMM (T2+T3+T4+T5 port).
// Block: 256 A-rows x 128 hid-cols, 8 waves, BK=32, 3-stage LDS pipeline,
// counted vmcnt(4) at tile boundary, both-sides XOR swizzle.
// ---------------------------------------------------------------------------
__global__ __launch_bounds__(512, 2)
void gemm_i2h_g8(const bf16* __restrict__ A, const bf16* __restrict__ W,
                 const float* __restrict__ bias, bf16* __restrict__ hid)
{
    __shared__ alignas(16) char smem[3 * 32768];   // per buf: A 16K | Bg 8K | Bl 8K
    const int tid  = threadIdx.x;
    const int lane = tid & 63, wid = tid >> 6;
    const int lrr  = lane & 15, lg = lane >> 4;
    const int wr = wid >> 2, wc = wid & 3;         // 2x4 wave grid
    const int row0 = blockIdx.x * 256;             // A rows
    const int colh = blockIdx.y * 128 + wc * 32;   // hid col base for this wave
    const int NT = 32;                             // K / 32

    const int cA0 = tid, cA1 = 512 + tid;
    const int rA0 = cA0 >> 2, rA1 = cA1 >> 2, rB = tid >> 2;
    const int swA0 = (((cA0 & 3) * 16) ^ (((rA0 >> 1) & 3) << 4)) >> 1;  // elems
    const int swA1 = (((cA1 & 3) * 16) ^ (((rA1 >> 1) & 3) << 4)) >> 1;
    const int swB  = (((tid & 3) * 16) ^ (((rB  >> 1) & 3) << 4)) >> 1;
    const bf16* gA0 = A + (size_t)(row0 + rA0) * 1024 + swA0;
    const bf16* gA1 = A + (size_t)(row0 + rA1) * 1024 + swA1;
    const bf16* gBg = W + (size_t)(blockIdx.y * 128 + rB) * 1024 + swB;
    const bf16* gBl = W + (size_t)(4096 + blockIdx.y * 128 + rB) * 1024 + swB;
    const int dA0 = (wid * 64) * 16, dA1 = (512 + wid * 64) * 16, dB = (wid * 64) * 16;

    f32x4 acc[8][4] = {};   // [m-frag][nv: 0,1 gate c0,c1; 2,3 lin c0,c1]

    {
        char* b0 = smem;
        GLD16(gBg, b0 + 16384 + dB); GLD16(gBl, b0 + 24576 + dB);
        GLD16(gA0, b0 + dA0);        GLD16(gA1, b0 + dA1);
        char* b1 = smem + 32768;
        GLD16(gBg + 32, b1 + 16384 + dB); GLD16(gBl + 32, b1 + 24576 + dB);
        GLD16(gA0 + 32, b1 + dA0);        GLD16(gA1 + 32, b1 + dA1);
    }
    asm volatile("s_waitcnt vmcnt(4)\ns_barrier" ::: "memory");

    int cur = 0, stg = 2;
    for (int t = 0; t < NT; ++t) {
        const char* bA  = smem + cur * 32768;
        const char* bBg = bA + 16384;
        const char* bBl = bA + 24576;
        char* sB = smem + stg * 32768;
        const int k0s = (t + 2) * 32;
        const bool dostg = (t < NT - 2);

        // phase 0: B frags + A frags m0..3
        if (dostg) { GLD16(gBg + k0s, sB + 16384 + dB); GLD16(gBl + k0s, sB + 24576 + dB); }
        bf16x8 bf[4], af[4];
        const int bcol = lg * 16;
#pragma unroll
        for (int nv = 0; nv < 4; ++nv) {
            const int row = wc * 32 + (nv & 1) * 16 + lrr;
            const char* base = (nv < 2) ? bBg : bBl;
            bf[nv] = *(const bf16x8*)(base + row * 64 + (bcol ^ (((row >> 1) & 3) << 4)));
        }
#pragma unroll
        for (int mi = 0; mi < 4; ++mi) {
            const int row = wr * 128 + mi * 16 + lrr;
            af[mi] = *(const bf16x8*)(bA + row * 64 + (bcol ^ (((row >> 1) & 3) << 4)));
        }
        __builtin_amdgcn_s_barrier();
        __builtin_amdgcn_s_setprio(1);
#pragma unroll
        for (int mi = 0; mi < 4; ++mi)
#pragma unroll
            for (int nv = 0; nv < 4; ++nv)
                acc[mi][nv] = __builtin_amdgcn_mfma_f32_16x16x32_bf16(
                    af[mi], bf[nv], acc[mi][nv], 0, 0, 0);
        __builtin_amdgcn_s_setprio(0);
        __builtin_amdgcn_s_barrier();

        // phase 1: A frags m4..7
        if (dostg) { GLD16(gA0 + k0s, sB + dA0); GLD16(gA1 + k0s, sB + dA1); }
#pragma unroll
        for (int mi = 0; mi < 4; ++mi) {
            const int row = wr * 128 + (4 + mi) * 16 + lrr;
            af[mi] = *(const bf16x8*)(bA + row * 64 + (bcol ^ (((row >> 1) & 3) << 4)));
        }
        __builtin_amdgcn_s_barrier();
        __builtin_amdgcn_s_setprio(1);
#pragma unroll
        for (int mi = 0; mi < 4; ++mi)
#pragma unroll
            for (int nv = 0; nv < 4; ++nv)
                acc[4 + mi][nv] = __builtin_amdgcn_mfma_f32_16x16x32_bf16(
                    af[mi], bf[nv], acc[4 + mi][nv], 0, 0, 0);
        __builtin_amdgcn_s_setprio(0);

        if (dostg) asm volatile("s_waitcnt vmcnt(4)\ns_barrier" ::: "memory");
        else       asm volatile("s_waitcnt vmcnt(0)\ns_barrier" ::: "memory");
        cur = (cur == 2) ? 0 : cur + 1;
        stg = (stg == 2) ? 0 : stg + 1;
    }

    // epilogue: hid = gelu(gate)*lin, fp32 pre-rounding
#pragma unroll
    for (int c = 0; c < 2; ++c) {
        const int gcol = colh + c * 16 + lrr;
        const float bg_ = bias[gcol], bl_ = bias[4096 + gcol];
#pragma unroll
        for (int mi = 0; mi < 8; ++mi)
#pragma unroll
            for (int r = 0; r < 4; ++r) {
                const size_t row = (size_t)(row0 + wr * 128 + mi * 16 + lg * 4 + r);
                const float g = acc[mi][c][r] + bg_;
                const float l = acc[mi][2 + c][r] + bl_;
                const float ge = 0.5f * g * (1.f + erff(g * 0.70710678118654752f));
                hid[row * 4096 + gcol] = (bf16)(ge * l);
            }
    }
}

// ---------------------------------------------------------------------------
// Flash attention, causal. Q pre-scaled by 1/8 in gemm_qkv_rope.
// Block = 4 waves = 64 q-rows of one (b,head). KV chunks of 64.
// ---------------------------------------------------------------------------
__global__ __launch_bounds__(256)
void attn_kernel(const bf16* __restrict__ q_r, const bf16* __restrict__ k_r,
                 const bf16* __restrict__ v_r, bf16* __restrict__ attn)
{
    __shared__ alignas(16) bf16 Ks[64][72];
    __shared__ alignas(16) bf16 Vt[64][72];
    __shared__ alignas(16) bf16 Ps[4][16][72];
    const int qt = blockIdx.x, bh = blockIdx.y;
    const int tid = threadIdx.x, lane = tid & 63, w = tid >> 6;
    const int lr = lane & 15, lg = lane >> 4;
    const int kgrp = lg * 8;
    const int qbase = qt * 64;

    const bf16* qrow = q_r + ((size_t)bh * 1024 + qbase + w * 16 + lr) * 64;
    const bf16x8 qf0 = *(const bf16x8*)(qrow + kgrp);
    const bf16x8 qf1 = *(const bf16x8*)(qrow + 32 + kgrp);

    f32x4 o[4] = {};
    float m_r[4], l_r[4];
#pragma unroll
    for (int r = 0; r < 4; ++r) { m_r[r] = -1e30f; l_r[r] = 0.f; }

    const int nchunk = qt + 1;
    for (int ic = 0; ic < nchunk; ++ic) {
        const int kb = ic * 64;
        __syncthreads();
#pragma unroll
        for (int i = 0; i < 2; ++i) {
            const int c = i * 256 + tid;
            const int row = c >> 3, e8 = (c & 7) * 8;
            *(bf16x8*)&Ks[row][e8] =
                *(const bf16x8*)(k_r + ((size_t)bh * 1024 + kb + row) * 64 + e8);
            const bf16x8 vv =
                *(const bf16x8*)(v_r + ((size_t)bh * 1024 + kb + row) * 64 + e8);
#pragma unroll
            for (int j = 0; j < 8; ++j) Vt[e8 + j][row] = vv[j];
        }
        __syncthreads();

        f32x4 sv[4] = {};
#pragma unroll
        for (int nb = 0; nb < 4; ++nb) {
            const bf16x8 kf0 = *(const bf16x8*)&Ks[nb * 16 + lr][kgrp];
            const bf16x8 kf1 = *(const bf16x8*)&Ks[nb * 16 + lr][32 + kgrp];
            sv[nb] = __builtin_amdgcn_mfma_f32_16x16x32_bf16(qf0, kf0, sv[nb], 0, 0, 0);
            sv[nb] = __builtin_amdgcn_mfma_f32_16x16x32_bf16(qf1, kf1, sv[nb], 0, 0, 0);
        }

        const bool diag = (kb == qbase);
        float pv[4][4];
#pragma unroll
        for (int r = 0; r < 4; ++r) {
            float s0[4];
#pragma unroll
            for (int nb = 0; nb < 4; ++nb) {
                float t = sv[nb][r];
                if (diag && (nb * 16 + lr) > (w * 16 + lg * 4 + r)) t = -10000.f;
                s0[nb] = t;
            }
            float rm = fmaxf(fmaxf(s0[0], s0[1]), fmaxf(s0[2], s0[3]));
#pragma unroll
            for (int off = 1; off < 16; off <<= 1) rm = fmaxf(rm, __shfl_xor(rm, off));
            const float nm = fmaxf(m_r[r], rm);
            const float sc = __expf(m_r[r] - nm);
            float rs = 0.f;
#pragma unroll
            for (int nb = 0; nb < 4; ++nb) {
                const float p = __expf(s0[nb] - nm);
                pv[nb][r] = p; rs += p;
            }
#pragma unroll
            for (int off = 1; off < 16; off <<= 1) rs += __shfl_xor(rs, off);
            l_r[r] = l_r[r] * sc + rs;
            m_r[r] = nm;
#pragma unroll
            for (int nb = 0; nb < 4; ++nb) o[nb][r] *= sc;
        }

#pragma unroll
        for (int nb = 0; nb < 4; ++nb)
#pragma unroll
            for (int r = 0; r < 4; ++r)
                Ps[w][lg * 4 + r][nb * 16 + lr] = (bf16)pv[nb][r];
#pragma unroll
        for (int nb = 0; nb < 4; ++nb)
#pragma unroll
            for (int ks = 0; ks < 2; ++ks) {
                const bf16x8 pa = *(const bf16x8*)&Ps[w][lr][ks * 32 + kgrp];
                const bf16x8 vb = *(const bf16x8*)&Vt[nb * 16 + lr][ks * 32 + kgrp];
                o[nb] = __builtin_amdgcn_mfma_f32_16x16x32_bf16(pa, vb, o[nb], 0, 0, 0);
            }
    }

    const int b = bh >> 4, head = bh & 15;
#pragma unroll
    for (int nb = 0; nb < 4; ++nb)
#pragma unroll
        for (int r = 0; r < 4; ++r) {
            const size_t rw = (size_t)(b * 1024 + qbase + w * 16 + lg * 4 + r);
            attn[rw * 1024 + head * 64 + nb * 16 + lr] = (bf16)(o[nb][r] / l_r[r]);
        }
}

// ---------------------------------------------------------------------------
extern "C" void kernel_launch(void* const* d_in, const int* in_sizes, int n_in,
                              void* d_out, int out_size, void* d_ws, size_t ws_size,
                              hipStream_t stream)
{
    const float* x    = (const float*)d_in[0];
    const float* ln1w = (const float*)d_in[1];
    const float* ln1b = (const float*)d_in[2];
    const float* qkvw = (const float*)d_in[3];
    const float* qkvb = (const float*)d_in[4];
    const float* outw = (const float*)d_in[5];
    const float* outb = (const float*)d_in[6];
    const float* ln2w = (const float*)d_in[7];
    const float* ln2b = (const float*)d_in[8];
    const float* i2hw = (const float*)d_in[9];
    const float* i2hb = (const float*)d_in[10];
    const float* h2ow = (const float*)d_in[11];
    const float* h2ob = (const float*)d_in[12];

    char* ws = (char*)d_ws;
    const size_t MB = 1024 * 1024;

    // [0,64) MB: phase-1 buffers, all dead before h2o -> reused as partials.
    bf16*  h_ln    = (bf16*)(ws + 0);         //  8 MB (dead after qkv_rope)
    bf16*  q_r     = (bf16*)(ws + 8 * MB);    //  8 MB (dead after attn)
    bf16*  k_r     = (bf16*)(ws + 16 * MB);   //  8 MB (dead after attn)
    bf16*  v_r     = (bf16*)(ws + 24 * MB);   //  8 MB (dead after attn)
    bf16*  attn    = (bf16*)(ws + 32 * MB);   //  8 MB (dead after outproj)
    bf16*  ffnln   = (bf16*)(ws + 40 * MB);   //  8 MB (dead after i2h)
    float* part    = (float*)(ws + 0);        // 64 MB (h2o split-K partials)
    bf16*  attnout = (bf16*)(ws + 64 * MB);   //  8 MB (live till end)
    bf16*  hid     = (bf16*)(ws + 72 * MB);   // 32 MB
    bf16*  qkvw_c  = (bf16*)(ws + 104 * MB);  //  6 MB
    bf16*  outw_c  = (bf16*)(ws + 110 * MB);  //  2 MB
    bf16*  i2hw_c  = (bf16*)(ws + 112 * MB);  // 16 MB
    bf16*  h2ow_c  = (bf16*)(ws + 128 * MB);  //  8 MB (total 136 MB)

    convert_kernel<<<1536, 256, 0, stream>>>(qkvw, qkvw_c, 3145728 / 8);
    convert_kernel<<< 512, 256, 0, stream>>>(outw, outw_c, 1048576 / 8);
    convert_kernel<<<4096, 256, 0, stream>>>(i2hw, i2hw_c, 8388608 / 8);
    convert_kernel<<<2048, 256, 0, stream>>>(h2ow, h2ow_c, 4194304 / 8);

    ln_kernel<float><<<4096, 256, 0, stream>>>(x, ln1w, ln1b, h_ln);
    gemm_qkv_rope<<<dim3(32, 24), 256, 0, stream>>>(h_ln, qkvw_c, qkvb,
                                                    q_r, k_r, v_r);
    attn_kernel<<<dim3(16, 64), 256, 0, stream>>>(q_r, k_r, v_r, attn);
    gemm_bt<1, false><<<dim3(32, 8), 256, 0, stream>>>(
        attn, outw_c, outb, x, attnout, 4096, 1024, 1024);
    ln_kernel<bf16><<<4096, 256, 0, stream>>>(attnout, ln2w, ln2b, ffnln);
    gemm_i2h_g8<<<dim3(16, 32), 512, 0, stream>>>(ffnln, i2hw_c, i2hb, hid);
    gemm_h2o_sk<<<dim3(32, 8, 4), 256, 0, stream>>>(hid, h2ow_c, part);
    h2o_reduce<<<4096, 256, 0, stream>>>(part, h2ob, attnout, (float*)d_out);
}

// Round 9
// 442.834 us; speedup vs baseline: 1.0951x; 1.0683x over previous
//
#include <hip/hip_runtime.h>
#include <cstdint>
#include <cstddef>

typedef __bf16 bf16;
typedef __bf16 bf16x4 __attribute__((ext_vector_type(4)));
typedef __bf16 bf16x8 __attribute__((ext_vector_type(8)));
typedef float  f32x4  __attribute__((ext_vector_type(4)));

// Direct global->LDS DMA, 16B per lane: HW writes (wave-uniform lds base) + lane*16.
#define GLD16(gptr, lptr)                                                      \
  __builtin_amdgcn_global_load_lds(                                            \
      (__attribute__((address_space(1))) unsigned int*)(gptr),                 \
      (__attribute__((address_space(3))) unsigned int*)(lptr), 16, 0, 0)

// ---------------------------------------------------------------------------
// fp32 -> bf16 conversion for the 4 big weight matrices (GLD16 needs bf16).
// ---------------------------------------------------------------------------
__global__ __launch_bounds__(256)
void convert_kernel(const float* __restrict__ src, bf16* __restrict__ dst, int n8)
{
    const int j = blockIdx.x * 256 + threadIdx.x;
    if (j >= n8) return;
    const float* s = src + (size_t)j * 8;
    bf16x8 o;
#pragma unroll
    for (int e = 0; e < 8; ++e) o[e] = (bf16)s[e];
    ((bf16x8*)dst)[j] = o;
}

// ---------------------------------------------------------------------------
// LayerNorm over H=1024, one block (256 thr) per row.
// ---------------------------------------------------------------------------
template<class InT>
__global__ __launch_bounds__(256)
void ln_kernel(const InT* __restrict__ x, const float* __restrict__ w,
               const float* __restrict__ b, bf16* __restrict__ out)
{
    __shared__ float red[8];
    const int row = blockIdx.x;
    const int tid = threadIdx.x;
    const InT* xr = x + (size_t)row * 1024;
    float xf[4], s = 0.f, ss = 0.f;
#pragma unroll
    for (int j = 0; j < 4; ++j) {
        xf[j] = (float)xr[tid * 4 + j];
        s += xf[j]; ss += xf[j] * xf[j];
    }
#pragma unroll
    for (int off = 32; off > 0; off >>= 1) { s += __shfl_xor(s, off); ss += __shfl_xor(ss, off); }
    if ((tid & 63) == 0) { red[(tid >> 6) * 2] = s; red[(tid >> 6) * 2 + 1] = ss; }
    __syncthreads();
    s  = red[0] + red[2] + red[4] + red[6];
    ss = red[1] + red[3] + red[5] + red[7];
    const float mu   = s * (1.f / 1024.f);
    const float var  = ss * (1.f / 1024.f) - mu * mu;
    const float rstd = rsqrtf(var + 1e-12f);
    bf16x4 ov;
#pragma unroll
    for (int j = 0; j < 4; ++j)
        ov[j] = (bf16)((xf[j] - mu) * rstd * w[tid * 4 + j] + b[tid * 4 + j]);
    *(bf16x4*)(out + (size_t)row * 1024 + tid * 4) = ov;
}

// ---------------------------------------------------------------------------
// m97-structure GEMM: C[M,N] = A[M,K] @ W[N,K]^T + bias (+ res).
// RES_MODE: 0 none, 1 fp32 residual, 2 bf16 residual. OUT_F32: fp32 store.
// ---------------------------------------------------------------------------
template<int RES_MODE, bool OUT_F32>
__global__ __launch_bounds__(256)
void gemm_bt(const bf16* __restrict__ A, const bf16* __restrict__ W,
             const float* __restrict__ bias, const void* __restrict__ res,
             void* __restrict__ Cv, int M, int N, int K)
{
    __shared__ alignas(16) bf16 As[128][32];
    __shared__ alignas(16) bf16 Bs[128][32];
    const int tid  = threadIdx.x;
    const int lane = tid & 63, wid = tid >> 6;
    const int lr = lane & 15, lg = lane >> 4;
    const int kgrp = lg * 8;
    const int wm = (wid >> 1) * 64, wn = (wid & 1) * 64;
    const int row0 = blockIdx.x * 128, col0 = blockIdx.y * 128;

    f32x4 acc[4][4] = {};

    for (int k0 = 0; k0 < K; k0 += 32) {
#pragma unroll
        for (int i = 0; i < 2; ++i) {
            const int c = i * 256 + tid;
            const int r = c >> 2, k8 = (c & 3) * 8;
            GLD16(A + (size_t)(row0 + r) * K + k0 + k8,
                  (char*)&As[0][0] + (size_t)(i * 256 + wid * 64) * 16);
            GLD16(W + (size_t)(col0 + r) * K + k0 + k8,
                  (char*)&Bs[0][0] + (size_t)(i * 256 + wid * 64) * 16);
        }
        __syncthreads();
        bf16x8 af[4], bw[4];
#pragma unroll
        for (int mi = 0; mi < 4; ++mi) af[mi] = *(const bf16x8*)&As[wm + mi * 16 + lr][kgrp];
#pragma unroll
        for (int ni = 0; ni < 4; ++ni) bw[ni] = *(const bf16x8*)&Bs[wn + ni * 16 + lr][kgrp];
#pragma unroll
        for (int mi = 0; mi < 4; ++mi)
#pragma unroll
            for (int ni = 0; ni < 4; ++ni)
                acc[mi][ni] = __builtin_amdgcn_mfma_f32_16x16x32_bf16(
                    af[mi], bw[ni], acc[mi][ni], 0, 0, 0);
        __syncthreads();
    }

    // C/D layout: col = lane&15, row = (lane>>4)*4 + reg
#pragma unroll
    for (int ni = 0; ni < 4; ++ni) {
        const int ccol = col0 + wn + ni * 16 + lr;
        const float bv = bias[ccol];
#pragma unroll
        for (int mi = 0; mi < 4; ++mi)
#pragma unroll
            for (int r = 0; r < 4; ++r) {
                const size_t crow = (size_t)(row0 + wm + mi * 16 + lg * 4 + r);
                float v = acc[mi][ni][r] + bv;
                if constexpr (RES_MODE == 1) v += ((const float*)res)[crow * N + ccol];
                if constexpr (RES_MODE == 2) v += (float)((const bf16*)res)[crow * N + ccol];
                if constexpr (OUT_F32) ((float*)Cv)[crow * N + ccol] = v;
                else                   ((bf16*)Cv)[crow * N + ccol] = (bf16)v;
            }
    }
}

// ---------------------------------------------------------------------------
// Split-K GEMM for h2o: M=4096, N=1024, K=4096 split into 4 x 1024.
// ---------------------------------------------------------------------------
__global__ __launch_bounds__(256)
void gemm_h2o_sk(const bf16* __restrict__ A, const bf16* __restrict__ W,
                 float* __restrict__ part)
{
    __shared__ alignas(16) bf16 As[128][32];
    __shared__ alignas(16) bf16 Bs[128][32];
    const int tid  = threadIdx.x;
    const int lane = tid & 63, wid = tid >> 6;
    const int lr = lane & 15, lg = lane >> 4;
    const int kgrp = lg * 8;
    const int wm = (wid >> 1) * 64, wn = (wid & 1) * 64;
    const int row0 = blockIdx.x * 128, col0 = blockIdx.y * 128;
    const int kbase = blockIdx.z * 1024;
    const int K = 4096;

    f32x4 acc[4][4] = {};

    for (int k0 = kbase; k0 < kbase + 1024; k0 += 32) {
#pragma unroll
        for (int i = 0; i < 2; ++i) {
            const int c = i * 256 + tid;
            const int r = c >> 2, k8 = (c & 3) * 8;
            GLD16(A + (size_t)(row0 + r) * K + k0 + k8,
                  (char*)&As[0][0] + (size_t)(i * 256 + wid * 64) * 16);
            GLD16(W + (size_t)(col0 + r) * K + k0 + k8,
                  (char*)&Bs[0][0] + (size_t)(i * 256 + wid * 64) * 16);
        }
        __syncthreads();
        bf16x8 af[4], bw[4];
#pragma unroll
        for (int mi = 0; mi < 4; ++mi) af[mi] = *(const bf16x8*)&As[wm + mi * 16 + lr][kgrp];
#pragma unroll
        for (int ni = 0; ni < 4; ++ni) bw[ni] = *(const bf16x8*)&Bs[wn + ni * 16 + lr][kgrp];
#pragma unroll
        for (int mi = 0; mi < 4; ++mi)
#pragma unroll
            for (int ni = 0; ni < 4; ++ni)
                acc[mi][ni] = __builtin_amdgcn_mfma_f32_16x16x32_bf16(
                    af[mi], bw[ni], acc[mi][ni], 0, 0, 0);
        __syncthreads();
    }

    float* dst = part + (size_t)blockIdx.z * 4096 * 1024;
#pragma unroll
    for (int ni = 0; ni < 4; ++ni) {
        const int ccol = col0 + wn + ni * 16 + lr;
#pragma unroll
        for (int mi = 0; mi < 4; ++mi)
#pragma unroll
            for (int r = 0; r < 4; ++r) {
                const size_t crow = (size_t)(row0 + wm + mi * 16 + lg * 4 + r);
                dst[crow * 1024 + ccol] = acc[mi][ni][r];
            }
    }
}

// ---------------------------------------------------------------------------
// Split-K reduce: out = sum(4 partials) + bias + attnout residual (fp32 out).
// ---------------------------------------------------------------------------
__global__ __launch_bounds__(256)
void h2o_reduce(const float* __restrict__ part, const float* __restrict__ bias,
                const bf16* __restrict__ res, float* __restrict__ out)
{
    const size_t g = ((size_t)blockIdx.x * 256 + threadIdx.x) * 4;
    const int col = (int)(g & 1023);
    f32x4 v = *(const f32x4*)(part + g);
#pragma unroll
    for (int s = 1; s < 4; ++s) {
        const f32x4 p = *(const f32x4*)(part + (size_t)s * 4096 * 1024 + g);
#pragma unroll
        for (int j = 0; j < 4; ++j) v[j] += p[j];
    }
    const f32x4 bv = *(const f32x4*)(bias + col);
    const bf16x4 rv = *(const bf16x4*)(res + g);
    f32x4 o;
#pragma unroll
    for (int j = 0; j < 4; ++j) o[j] = v[j] + bv[j] + (float)rv[j];
    *(f32x4*)(out + g) = o;
}

// ---------------------------------------------------------------------------
// QKV GEMM with fused RoPE + head-rearrange + q-scale epilogue.
// ---------------------------------------------------------------------------
__global__ __launch_bounds__(256)
void gemm_qkv_rope(const bf16* __restrict__ A, const bf16* __restrict__ W,
                   const float* __restrict__ bias, bf16* __restrict__ q_r,
                   bf16* __restrict__ k_r, bf16* __restrict__ v_r)
{
    __shared__ alignas(16) bf16 As[128][32];
    __shared__ alignas(16) bf16 Bs[128][32];
    const int tid  = threadIdx.x;
    const int lane = tid & 63, wid = tid >> 6;
    const int lr = lane & 15, lg = lane >> 4;
    const int kgrp = lg * 8;
    const int wm = (wid >> 1) * 64, wn = (wid & 1) * 64;
    const int row0 = blockIdx.x * 128, col0 = blockIdx.y * 128;
    const int K = 1024;

    f32x4 acc[4][4] = {};

    for (int k0 = 0; k0 < K; k0 += 32) {
#pragma unroll
        for (int i = 0; i < 2; ++i) {
            const int c = i * 256 + tid;
            const int r = c >> 2, k8 = (c & 3) * 8;
            GLD16(A + (size_t)(row0 + r) * K + k0 + k8,
                  (char*)&As[0][0] + (size_t)(i * 256 + wid * 64) * 16);
            GLD16(W + (size_t)(col0 + r) * K + k0 + k8,
                  (char*)&Bs[0][0] + (size_t)(i * 256 + wid * 64) * 16);
        }
        __syncthreads();
        bf16x8 af[4], bw[4];
#pragma unroll
        for (int mi = 0; mi < 4; ++mi) af[mi] = *(const bf16x8*)&As[wm + mi * 16 + lr][kgrp];
#pragma unroll
        for (int ni = 0; ni < 4; ++ni) bw[ni] = *(const bf16x8*)&Bs[wn + ni * 16 + lr][kgrp];
#pragma unroll
        for (int mi = 0; mi < 4; ++mi)
#pragma unroll
            for (int ni = 0; ni < 4; ++ni)
                acc[mi][ni] = __builtin_amdgcn_mfma_f32_16x16x32_bf16(
                    af[mi], bw[ni], acc[mi][ni], 0, 0, 0);
        __syncthreads();
    }

    const int third = blockIdx.y >> 3;               // 0 q, 1 k, 2 v
    bf16* dst = (third == 0) ? q_r : (third == 1) ? k_r : v_r;
    const float qs = (third == 0) ? 0.125f : 1.f;    // folded softmax scale
#pragma unroll
    for (int ni = 0; ni < 2; ++ni) {
        const int i_ = ni * 16 + lr;
        const int ccol = col0 + wn + ni * 16 + lr;
        const int h = (ccol >> 6) & 15;
        const float blo = bias[ccol], bhi = bias[ccol + 32];
        const float inv = __expf((float)i_ * (-9.210340371976184f / 32.f));
#pragma unroll
        for (int mi = 0; mi < 4; ++mi)
#pragma unroll
            for (int r = 0; r < 4; ++r) {
                const int crow = row0 + wm + mi * 16 + lg * 4 + r;
                const int s = crow & 1023, b = crow >> 10;
                const float lo = acc[mi][ni][r] + blo;
                const float hi = acc[mi][ni + 2][r] + bhi;
                const size_t ob = ((size_t)(b * 16 + h) * 1024 + s) * 64;
                if (third == 2) {
                    dst[ob + i_]      = (bf16)lo;
                    dst[ob + i_ + 32] = (bf16)hi;
                } else {
                    float sn, c;
                    sincosf((float)s * inv, &sn, &c);
                    dst[ob + i_]      = (bf16)((lo * c - hi * sn) * qs);
                    dst[ob + i_ + 32] = (bf16)((hi * c + lo * sn) * qs);
                }
            }
    }
}

// ---------------------------------------------------------------------------
// i2h + gated exact-GELU, pipelined GEMM (unchanged from R8).
// ---------------------------------------------------------------------------
__global__ __launch_bounds__(512, 2)
void gemm_i2h_g8(const bf16* __restrict__ A, const bf16* __restrict__ W,
                 const float* __restrict__ bias, bf16* __restrict__ hid)
{
    __shared__ alignas(16) char smem[3 * 32768];
    const int tid  = threadIdx.x;
    const int lane = tid & 63, wid = tid >> 6;
    const int lrr  = lane & 15, lg = lane >> 4;
    const int wr = wid >> 2, wc = wid & 3;
    const int row0 = blockIdx.x * 256;
    const int colh = blockIdx.y * 128 + wc * 32;
    const int NT = 32;

    const int cA0 = tid, cA1 = 512 + tid;
    const int rA0 = cA0 >> 2, rA1 = cA1 >> 2, rB = tid >> 2;
    const int swA0 = (((cA0 & 3) * 16) ^ (((rA0 >> 1) & 3) << 4)) >> 1;
    const int swA1 = (((cA1 & 3) * 16) ^ (((rA1 >> 1) & 3) << 4)) >> 1;
    const int swB  = (((tid & 3) * 16) ^ (((rB  >> 1) & 3) << 4)) >> 1;
    const bf16* gA0 = A + (size_t)(row0 + rA0) * 1024 + swA0;
    const bf16* gA1 = A + (size_t)(row0 + rA1) * 1024 + swA1;
    const bf16* gBg = W + (size_t)(blockIdx.y * 128 + rB) * 1024 + swB;
    const bf16* gBl = W + (size_t)(4096 + blockIdx.y * 128 + rB) * 1024 + swB;
    const int dA0 = (wid * 64) * 16, dA1 = (512 + wid * 64) * 16, dB = (wid * 64) * 16;

    f32x4 acc[8][4] = {};

    {
        char* b0 = smem;
        GLD16(gBg, b0 + 16384 + dB); GLD16(gBl, b0 + 24576 + dB);
        GLD16(gA0, b0 + dA0);        GLD16(gA1, b0 + dA1);
        char* b1 = smem + 32768;
        GLD16(gBg + 32, b1 + 16384 + dB); GLD16(gBl + 32, b1 + 24576 + dB);
        GLD16(gA0 + 32, b1 + dA0);        GLD16(gA1 + 32, b1 + dA1);
    }
    asm volatile("s_waitcnt vmcnt(4)\ns_barrier" ::: "memory");

    int cur = 0, stg = 2;
    for (int t = 0; t < NT; ++t) {
        const char* bA  = smem + cur * 32768;
        const char* bBg = bA + 16384;
        const char* bBl = bA + 24576;
        char* sB = smem + stg * 32768;
        const int k0s = (t + 2) * 32;
        const bool dostg = (t < NT - 2);

        if (dostg) { GLD16(gBg + k0s, sB + 16384 + dB); GLD16(gBl + k0s, sB + 24576 + dB); }
        bf16x8 bf[4], af[4];
        const int bcol = lg * 16;
#pragma unroll
        for (int nv = 0; nv < 4; ++nv) {
            const int row = wc * 32 + (nv & 1) * 16 + lrr;
            const char* base = (nv < 2) ? bBg : bBl;
            bf[nv] = *(const bf16x8*)(base + row * 64 + (bcol ^ (((row >> 1) & 3) << 4)));
        }
#pragma unroll
        for (int mi = 0; mi < 4; ++mi) {
            const int row = wr * 128 + mi * 16 + lrr;
            af[mi] = *(const bf16x8*)(bA + row * 64 + (bcol ^ (((row >> 1) & 3) << 4)));
        }
        __builtin_amdgcn_s_barrier();
        __builtin_amdgcn_s_setprio(1);
#pragma unroll
        for (int mi = 0; mi < 4; ++mi)
#pragma unroll
            for (int nv = 0; nv < 4; ++nv)
                acc[mi][nv] = __builtin_amdgcn_mfma_f32_16x16x32_bf16(
                    af[mi], bf[nv], acc[mi][nv], 0, 0, 0);
        __builtin_amdgcn_s_setprio(0);
        __builtin_amdgcn_s_barrier();

        if (dostg) { GLD16(gA0 + k0s, sB + dA0); GLD16(gA1 + k0s, sB + dA1); }
#pragma unroll
        for (int mi = 0; mi < 4; ++mi) {
            const int row = wr * 128 + (4 + mi) * 16 + lrr;
            af[mi] = *(const bf16x8*)(bA + row * 64 + (bcol ^ (((row >> 1) & 3) << 4)));
        }
        __builtin_amdgcn_s_barrier();
        __builtin_amdgcn_s_setprio(1);
#pragma unroll
        for (int mi = 0; mi < 4; ++mi)
#pragma unroll
            for (int nv = 0; nv < 4; ++nv)
                acc[4 + mi][nv] = __builtin_amdgcn_mfma_f32_16x16x32_bf16(
                    af[mi], bf[nv], acc[4 + mi][nv], 0, 0, 0);
        __builtin_amdgcn_s_setprio(0);

        if (dostg) asm volatile("s_waitcnt vmcnt(4)\ns_barrier" ::: "memory");
        else       asm volatile("s_waitcnt vmcnt(0)\ns_barrier" ::: "memory");
        cur = (cur == 2) ? 0 : cur + 1;
        stg = (stg == 2) ? 0 : stg + 1;
    }

#pragma unroll
    for (int c = 0; c < 2; ++c) {
        const int gcol = colh + c * 16 + lrr;
        const float bg_ = bias[gcol], bl_ = bias[4096 + gcol];
#pragma unroll
        for (int mi = 0; mi < 8; ++mi)
#pragma unroll
            for (int r = 0; r < 4; ++r) {
                const size_t row = (size_t)(row0 + wr * 128 + mi * 16 + lg * 4 + r);
                const float g = acc[mi][c][r] + bg_;
                const float l = acc[mi][2 + c][r] + bl_;
                const float ge = 0.5f * g * (1.f + erff(g * 0.70710678118654752f));
                hid[row * 4096 + gcol] = (bf16)(ge * l);
            }
    }
}

// ---------------------------------------------------------------------------
// Flash attention v2: causal, q pre-scaled.
// Grid (8, 64): block p handles q-tiles qt_hi=15-p (chunks 0..15-p) and
// qt_lo=p (accumulated when ic<=p) -> uniform 17 tile-computes/block
// (R8 counter: Occupancy 13% from 16:1 qt imbalance). K/V staged once, shared.
// Vt stored with col8-XOR swizzle: addr(d,s)=d*72+(((s>>3)^(d>>3))<<3)+(s&7)
// -> scatter stores hit all 32 banks (2-way, free) instead of 4 banks
// (16-way; R8 counter: 1.03e7 SQ_LDS_BANK_CONFLICT ~= 1184 cyc/chunk).
// ---------------------------------------------------------------------------
__global__ __launch_bounds__(256)
void attn_kernel(const bf16* __restrict__ q_r, const bf16* __restrict__ k_r,
                 const bf16* __restrict__ v_r, bf16* __restrict__ attn)
{
    __shared__ alignas(16) bf16 Ks[64][72];
    __shared__ alignas(16) bf16 Vt[64 * 72];     // swizzled V^T [hd][kv]
    __shared__ alignas(16) bf16 Ps[4][16][72];
    const int p = blockIdx.x, bh = blockIdx.y;
    const int tid = threadIdx.x, lane = tid & 63, w = tid >> 6;
    const int lr = lane & 15, lg = lane >> 4;
    const int kgrp = lg * 8;
    const int qt_hi = 15 - p, qt_lo = p;
    const int qbh = qt_hi * 64, qbl = qt_lo * 64;

    const bf16* qrowh = q_r + ((size_t)bh * 1024 + qbh + w * 16 + lr) * 64;
    const bf16x8 qh0 = *(const bf16x8*)(qrowh + kgrp);
    const bf16x8 qh1 = *(const bf16x8*)(qrowh + 32 + kgrp);
    const bf16* qrowl = q_r + ((size_t)bh * 1024 + qbl + w * 16 + lr) * 64;
    const bf16x8 ql0 = *(const bf16x8*)(qrowl + kgrp);
    const bf16x8 ql1 = *(const bf16x8*)(qrowl + 32 + kgrp);

    f32x4 oh[4] = {}, ol[4] = {};
    float mh[4], lh[4], ml[4], ll[4];
#pragma unroll
    for (int r = 0; r < 4; ++r) { mh[r] = -1e30f; lh[r] = 0.f; ml[r] = -1e30f; ll[r] = 0.f; }

    const int myrow = w * 16 + lg * 4;   // q-row base (mod tile) this thread owns

    for (int ic = 0; ic <= qt_hi; ++ic) {
        const int kb = ic * 64;
        __syncthreads();   // previous chunk fully consumed
#pragma unroll
        for (int i = 0; i < 2; ++i) {
            const int c = i * 256 + tid;
            const int row = c >> 3, e8 = (c & 7) * 8;   // row=kv, e8=hd base
            *(bf16x8*)&Ks[row][e8] =
                *(const bf16x8*)(k_r + ((size_t)bh * 1024 + kb + row) * 64 + e8);
            const bf16x8 vv =
                *(const bf16x8*)(v_r + ((size_t)bh * 1024 + kb + row) * 64 + e8);
            const int s8 = row >> 3, s7 = row & 7;
#pragma unroll
            for (int j = 0; j < 8; ++j) {
                const int d = e8 + j;
                Vt[d * 72 + ((s8 ^ (d >> 3)) << 3) + s7] = vv[j];
            }
        }
        __syncthreads();

        // shared K fragments for this chunk
        bf16x8 kf0[4], kf1[4];
#pragma unroll
        for (int nb = 0; nb < 4; ++nb) {
            kf0[nb] = *(const bf16x8*)&Ks[nb * 16 + lr][kgrp];
            kf1[nb] = *(const bf16x8*)&Ks[nb * 16 + lr][32 + kgrp];
        }
        // V^T fragments (swizzled read)
        bf16x8 vf[4][2];
#pragma unroll
        for (int nb = 0; nb < 4; ++nb) {
            const int d = nb * 16 + lr, dh = d >> 3;
#pragma unroll
            for (int ks = 0; ks < 2; ++ks)
                vf[nb][ks] = *(const bf16x8*)&Vt[d * 72 + (((ks * 4 + lg) ^ dh) << 3)];
        }

#pragma unroll
        for (int half = 0; half < 2; ++half) {
            if (half == 1 && ic > qt_lo) break;
            const bf16x8 qf0 = half ? ql0 : qh0;
            const bf16x8 qf1 = half ? ql1 : qh1;
            const bool diag = half ? (ic == qt_lo) : (ic == qt_hi);
            float* m_r = half ? ml : mh;
            float* l_r = half ? ll : lh;
            f32x4* o = half ? ol : oh;

            f32x4 sv[4] = {};
#pragma unroll
            for (int nb = 0; nb < 4; ++nb) {
                sv[nb] = __builtin_amdgcn_mfma_f32_16x16x32_bf16(qf0, kf0[nb], sv[nb], 0, 0, 0);
                sv[nb] = __builtin_amdgcn_mfma_f32_16x16x32_bf16(qf1, kf1[nb], sv[nb], 0, 0, 0);
            }

            float pv[4][4];
#pragma unroll
            for (int r = 0; r < 4; ++r) {
                float s0[4];
#pragma unroll
                for (int nb = 0; nb < 4; ++nb) {
                    float t = sv[nb][r];
                    if (diag && (nb * 16 + lr) > (myrow + r)) t = -10000.f;
                    s0[nb] = t;
                }
                float rm = fmaxf(fmaxf(s0[0], s0[1]), fmaxf(s0[2], s0[3]));
#pragma unroll
                for (int off = 1; off < 16; off <<= 1) rm = fmaxf(rm, __shfl_xor(rm, off));
                const float nm = fmaxf(m_r[r], rm);
                const float sc = __expf(m_r[r] - nm);
                float rs = 0.f;
#pragma unroll
                for (int nb = 0; nb < 4; ++nb) {
                    const float pe = __expf(s0[nb] - nm);
                    pv[nb][r] = pe; rs += pe;
                }
#pragma unroll
                for (int off = 1; off < 16; off <<= 1) rs += __shfl_xor(rs, off);
                l_r[r] = l_r[r] * sc + rs;
                m_r[r] = nm;
#pragma unroll
                for (int nb = 0; nb < 4; ++nb) o[nb][r] *= sc;
            }

#pragma unroll
            for (int nb = 0; nb < 4; ++nb)
#pragma unroll
                for (int r = 0; r < 4; ++r)
                    Ps[w][lg * 4 + r][nb * 16 + lr] = (bf16)pv[nb][r];
#pragma unroll
            for (int nb = 0; nb < 4; ++nb)
#pragma unroll
                for (int ks = 0; ks < 2; ++ks) {
                    const bf16x8 pa = *(const bf16x8*)&Ps[w][lr][ks * 32 + kgrp];
                    o[nb] = __builtin_amdgcn_mfma_f32_16x16x32_bf16(pa, vf[nb][ks], o[nb], 0, 0, 0);
                }
        }
    }

    // write both tiles, [b, s, h] layout
    const int b = bh >> 4, head = bh & 15;
#pragma unroll
    for (int half = 0; half < 2; ++half) {
        const int qb = half ? qbl : qbh;
        const f32x4* o = half ? ol : oh;
        const float* l_r = half ? ll : lh;
#pragma unroll
        for (int nb = 0; nb < 4; ++nb)
#pragma unroll
            for (int r = 0; r < 4; ++r) {
                const size_t rw = (size_t)(b * 1024 + qb + myrow + r);
                attn[rw * 1024 + head * 64 + nb * 16 + lr] = (bf16)(o[nb][r] / l_r[r]);
            }
    }
}

// ---------------------------------------------------------------------------
extern "C" void kernel_launch(void* const* d_in, const int* in_sizes, int n_in,
                              void* d_out, int out_size, void* d_ws, size_t ws_size,
                              hipStream_t stream)
{
    const float* x    = (const float*)d_in[0];
    const float* ln1w = (const float*)d_in[1];
    const float* ln1b = (const float*)d_in[2];
    const float* qkvw = (const float*)d_in[3];
    const float* qkvb = (const float*)d_in[4];
    const float* outw = (const float*)d_in[5];
    const float* outb = (const float*)d_in[6];
    const float* ln2w = (const float*)d_in[7];
    const float* ln2b = (const float*)d_in[8];
    const float* i2hw = (const float*)d_in[9];
    const float* i2hb = (const float*)d_in[10];
    const float* h2ow = (const float*)d_in[11];
    const float* h2ob = (const float*)d_in[12];

    char* ws = (char*)d_ws;
    const size_t MB = 1024 * 1024;

    // [0,64) MB: phase-1 buffers, all dead before h2o -> reused as partials.
    bf16*  h_ln    = (bf16*)(ws + 0);         //  8 MB (dead after qkv_rope)
    bf16*  q_r     = (bf16*)(ws + 8 * MB);    //  8 MB (dead after attn)
    bf16*  k_r     = (bf16*)(ws + 16 * MB);   //  8 MB (dead after attn)
    bf16*  v_r     = (bf16*)(ws + 24 * MB);   //  8 MB (dead after attn)
    bf16*  attn    = (bf16*)(ws + 32 * MB);   //  8 MB (dead after outproj)
    bf16*  ffnln   = (bf16*)(ws + 40 * MB);   //  8 MB (dead after i2h)
    float* part    = (float*)(ws + 0);        // 64 MB (h2o split-K partials)
    bf16*  attnout = (bf16*)(ws + 64 * MB);   //  8 MB (live till end)
    bf16*  hid     = (bf16*)(ws + 72 * MB);   // 32 MB
    bf16*  qkvw_c  = (bf16*)(ws + 104 * MB);  //  6 MB
    bf16*  outw_c  = (bf16*)(ws + 110 * MB);  //  2 MB
    bf16*  i2hw_c  = (bf16*)(ws + 112 * MB);  // 16 MB
    bf16*  h2ow_c  = (bf16*)(ws + 128 * MB);  //  8 MB (total 136 MB)

    convert_kernel<<<1536, 256, 0, stream>>>(qkvw, qkvw_c, 3145728 / 8);
    convert_kernel<<< 512, 256, 0, stream>>>(outw, outw_c, 1048576 / 8);
    convert_kernel<<<4096, 256, 0, stream>>>(i2hw, i2hw_c, 8388608 / 8);
    convert_kernel<<<2048, 256, 0, stream>>>(h2ow, h2ow_c, 4194304 / 8);

    ln_kernel<float><<<4096, 256, 0, stream>>>(x, ln1w, ln1b, h_ln);
    gemm_qkv_rope<<<dim3(32, 24), 256, 0, stream>>>(h_ln, qkvw_c, qkvb,
                                                    q_r, k_r, v_r);
    attn_kernel<<<dim3(8, 64), 256, 0, stream>>>(q_r, k_r, v_r, attn);
    gemm_bt<1, false><<<dim3(32, 8), 256, 0, stream>>>(
        attn, outw_c, outb, x, attnout, 4096, 1024, 1024);
    ln_kernel<bf16><<<4096, 256, 0, stream>>>(attnout, ln2w, ln2b, ffnln);
    gemm_i2h_g8<<<dim3(16, 32), 512, 0, stream>>>(ffnln, i2hw_c, i2hb, hid);
    gemm_h2o_sk<<<dim3(32, 8, 4), 256, 0, stream>>>(hid, h2ow_c, part);
    h2o_reduce<<<4096, 256, 0, stream>>>(part, h2ob, attnout, (float*)d_out);
}